// Round 17
// baseline (106.619 us; speedup 1.0000x reference)
//
#include <hip/hip_runtime.h>
#include <cstdint>
#include <cstddef>

// ---------------- problem dims ----------------
#define S_LEN 2048
#define NHEAD 16
#define HDIM  64
#define EMB   1024
#define MROWS 4096   // B*S
#define KDIM  1024

typedef __bf16 bf16;
typedef unsigned int u32;
typedef __attribute__((ext_vector_type(8)))  __bf16 bf16x8;
typedef __attribute__((ext_vector_type(4)))  __bf16 bf16x4;
typedef __attribute__((ext_vector_type(4)))  float  f32x4;
typedef __attribute__((ext_vector_type(16))) float  f32x16;
typedef __attribute__((ext_vector_type(4)))  u32    u32x4;

__device__ __forceinline__ f32x4 mfma_16x16x32(bf16x8 a, bf16x8 b, f32x4 c) {
  return __builtin_amdgcn_mfma_f32_16x16x32_bf16(a, b, c, 0, 0, 0);
}
__device__ __forceinline__ f32x16 mfma32(bf16x8 a, bf16x8 b, f32x16 c) {
  return __builtin_amdgcn_mfma_f32_32x32x16_bf16(a, b, c, 0, 0, 0);
}
__device__ __forceinline__ u32 cvt_pk_bf16(float lo, float hi) {
  u32 r;
  asm("v_cvt_pk_bf16_f32 %0, %1, %2" : "=v"(r) : "v"(lo), "v"(hi));
  return r;
}
__device__ __forceinline__ f32x16 fz16() {
  f32x16 z;
#pragma unroll
  for (int i = 0; i < 16; i++) z[i] = 0.f;
  return z;
}

// async global->LDS, 16B per lane; lds ptr must be wave-uniform base (HW adds lane*16)
__device__ __forceinline__ void gload16(const bf16* g, void* lds_uniform) {
  __builtin_amdgcn_global_load_lds(
      (const __attribute__((address_space(1))) void*)g,
      (__attribute__((address_space(3))) void*)lds_uniform, 16, 0, 0);
}

// ---------------- prep: x fp32 -> bf16 ----------------
__global__ void prep_x_kernel(const float* __restrict__ x, bf16* __restrict__ xb) {
  int idx = blockIdx.x * blockDim.x + threadIdx.x;   // 0 .. 512K-1, 8 elems each
  const float4* x4 = (const float4*)x;
  float4 a = x4[idx * 2 + 0];
  float4 b = x4[idx * 2 + 1];
  bf16x8 v;
  v[0] = (bf16)a.x; v[1] = (bf16)a.y; v[2] = (bf16)a.z; v[3] = (bf16)a.w;
  v[4] = (bf16)b.x; v[5] = (bf16)b.y; v[6] = (bf16)b.z; v[7] = (bf16)b.w;
  *(bf16x8*)(xb + (size_t)idx * 8) = v;
}

// ---------------- prep: W [K,N] fp32 -> Wt [N,K] bf16, LDS-tiled transpose ----------------
__global__ void prep_w_kernel(const float* __restrict__ Wq, const float* __restrict__ Wk,
                              const float* __restrict__ Wv, const float* __restrict__ Wo,
                              bf16* __restrict__ wqkvt, bf16* __restrict__ wot) {
  __shared__ float tile[64][65];
  int mat = blockIdx.z;
  const float* W = (mat == 0) ? Wq : (mat == 1) ? Wk : (mat == 2) ? Wv : Wo;
  bf16* dst = (mat < 3) ? (wqkvt + (size_t)mat * 1024 * 1024) : wot;
  int k0 = blockIdx.x * 64, r0 = blockIdx.y * 64;
  int tid = threadIdx.x;
#pragma unroll
  for (int i = 0; i < 16; i++) {
    int idx = i * 256 + tid;
    int kk = idx >> 6, rr = idx & 63;
    tile[kk][rr] = W[(size_t)(k0 + kk) * 1024 + r0 + rr];
  }
  __syncthreads();
#pragma unroll
  for (int i = 0; i < 16; i++) {
    int idx = i * 256 + tid;
    int rr = idx >> 6, kk = idx & 63;
    dst[(size_t)(r0 + rr) * 1024 + k0 + kk] = (bf16)tile[kk][rr];
  }
}

// ---------------- GEMM: C[m,n] = sum_k A[m,k]*Bt[n,k] (+bias) ----------------
// MODE 0: QKV epilogue (bias + bf16; Q scaled by log2(e)/8; Q/K [B,H,S,D], V [B,H,D,S])
// MODE 1: out epilogue (bias + fp32 to d_out)
template <int MODE>
__global__ __launch_bounds__(256, 2) void gemm_bt(
    const bf16* __restrict__ A, const bf16* __restrict__ Bt,
    const float* __restrict__ b0, const float* __restrict__ b1, const float* __restrict__ b2,
    float* __restrict__ outf,
    bf16* __restrict__ qo, bf16* __restrict__ ko, bf16* __restrict__ vto) {
  __shared__ bf16 lA[128 * 64];
  __shared__ bf16 lB[128 * 64];
  const int bm = blockIdx.x, bn = blockIdx.y;
  const int tid = threadIdx.x;
  const int w = tid >> 6, l = tid & 63;
  const int wm = w >> 1, wn = w & 1;
  const int lr = l & 15, lg = l >> 4;

  f32x4 zero = {0.f, 0.f, 0.f, 0.f};
  f32x4 acc[4][4];
#pragma unroll
  for (int i = 0; i < 4; i++)
#pragma unroll
    for (int j = 0; j < 4; j++) acc[i][j] = zero;

  char* lAb = (char*)lA;
  char* lBb = (char*)lB;
  const size_t a_row0 = (size_t)bm * 128;
  const size_t b_row0 = (size_t)bn * 128;

  for (int kt = 0; kt < KDIM; kt += 64) {
    __syncthreads();
#pragma unroll
    for (int i = 0; i < 4; i++) {
      int cq = i * 256 + tid;
      int row = cq >> 3;
      int c8 = (cq & 7) ^ (row & 7);
      gload16(A + (a_row0 + row) * KDIM + kt + c8 * 8, lAb + (i * 256 + w * 64) * 16);
    }
#pragma unroll
    for (int i = 0; i < 4; i++) {
      int cq = i * 256 + tid;
      int row = cq >> 3;
      int c8 = (cq & 7) ^ (row & 7);
      gload16(Bt + (b_row0 + row) * KDIM + kt + c8 * 8, lBb + (i * 256 + w * 64) * 16);
    }
    asm volatile("s_waitcnt vmcnt(0)" ::: "memory");
    __syncthreads();

#pragma unroll
    for (int kk = 0; kk < 2; kk++) {
      bf16x8 af[4], bfv[4];
#pragma unroll
      for (int i = 0; i < 4; i++) {
        int row = wm * 64 + i * 16 + lr;
        af[i] = *(const bf16x8*)(lAb + row * 128 + ((((kk << 2) + lg) ^ (row & 7)) << 4));
      }
#pragma unroll
      for (int j = 0; j < 4; j++) {
        int row = wn * 64 + j * 16 + lr;
        bfv[j] = *(const bf16x8*)(lBb + row * 128 + ((((kk << 2) + lg) ^ (row & 7)) << 4));
      }
#pragma unroll
      for (int i = 0; i < 4; i++)
#pragma unroll
        for (int j = 0; j < 4; j++) acc[i][j] = mfma_16x16x32(af[i], bfv[j], acc[i][j]);
    }
  }

  // epilogue: C frag layout col = l&15, row = (l>>4)*4 + reg
#pragma unroll
  for (int i = 0; i < 4; i++) {
#pragma unroll
    for (int j = 0; j < 4; j++) {
      int n = bn * 128 + wn * 64 + j * 16 + lr;
      int mbase = bm * 128 + wm * 64 + i * 16 + lg * 4;
      if (MODE == 1) {
#pragma unroll
        for (int jj = 0; jj < 4; jj++)
          outf[(size_t)(mbase + jj) * 1024 + n] = acc[i][j][jj] + b0[n];
      } else {
        int p = n >> 10, nn = n & 1023;
        int h = nn >> 6, d = nn & 63;
        int b = mbase >> 11, s = mbase & 2047;
        const float* bp = (p == 0) ? b0 : (p == 1) ? b1 : b2;
        float bias = bp[nn];
        if (p == 2) {
          bf16x4 pk;
#pragma unroll
          for (int jj = 0; jj < 4; jj++) pk[jj] = (bf16)(acc[i][j][jj] + bias);
          *(bf16x4*)(vto + (((size_t)(b * 16 + h)) * 64 + d) * 2048 + s) = pk;
        } else {
          // fold softmax scale log2(e)/sqrt(64) into Q (fp32, before the bf16 round)
          float qsc = (p == 0) ? 0.18033688011112042f : 1.0f;
          bf16* o = (p == 0) ? qo : ko;
#pragma unroll
          for (int jj = 0; jj < 4; jj++)
            o[(((size_t)(b * 16 + h)) * 2048 + s + jj) * 64 + d] =
                (bf16)((acc[i][j][jj] + bias) * qsc);
        }
      }
    }
  }
}

// ---------------- flash attention v12: KV-split x2, FIXED buffer offsets ----------------
// R16's failure was mechanical: 2 buffers are 16KB each (K 8KB | V 8KB), so the
// buffer byte offset is beta<<14; R16 used <<13, making buf1's K overlap buf0's V
// (STAGE(t+1) async-overwrote the V being read by COMPUTE(t) in the same iter).
// No-max softmax => partials PURELY ADDITIVE: O = (o_A + o_B)/(l_A + l_B).
// Each block does 16 of 32 KV tiles; grid 1024 = 4 blocks/CU = 4 waves/SIMD
// (2x R15's TLP; R15 counters: MfmaUtil 36.9% == serial-chain MFMA share).
// COMPUTE math byte-identical to R15. LDS 32KB (2 bufs), distance-1 prefetch,
// vmcnt(0)+s_barrier per tile. Partials written in OBUF LAYOUT: sp=0 -> po0
// (dead xb region), sp=1 -> obuf directly; combine normalizes obuf in place
// (same-index element-wise => race-free). ws stays at the proven 48 MB.
__global__ __launch_bounds__(256, 4) void attn_kernel(
    const bf16* __restrict__ qb, const bf16* __restrict__ kb,
    const bf16* __restrict__ vtb, bf16* __restrict__ po0, bf16* __restrict__ po1,
    float* __restrict__ plb) {
  __shared__ bf16 lKV[2 * 8192];     // 32 KB: 2 buffers x 16KB (K 8KB | V 8KB)
  const int bid = blockIdx.x;                      // 0..1023
  const int work = ((bid & 7) << 7) | (bid >> 3);  // 8 XCDs x 128 contiguous works
  const int qt = work & 15;
  const int bh = (work >> 4) & 31;
  const int sp = work >> 9;                        // KV split half: 0 or 1
  const int tid = threadIdx.x;
  const int w = tid >> 6, l = tid & 63;
  const int l5 = l >> 5, l31 = l & 31;

  const bf16* Qh = qb + (size_t)bh * S_LEN * HDIM;
  const bf16* Kh = kb + (size_t)bh * S_LEN * HDIM;
  const bf16* Vh = vtb + (size_t)bh * HDIM * S_LEN;

  // Q as B-fragment (pre-scaled by log2(e)/8): lane holds Q[q=l31][16c + 8*l5 + e]
  const int qrow = qt * 128 + w * 32 + l31;
  const bf16* qp = Qh + (size_t)qrow * 64 + l5 * 8;
  bf16x8 qf0 = *(const bf16x8*)(qp);
  bf16x8 qf1 = *(const bf16x8*)(qp + 16);
  bf16x8 qf2 = *(const bf16x8*)(qp + 32);
  bf16x8 qf3 = *(const bf16x8*)(qp + 48);

  bf16x8 ones;
#pragma unroll
  for (int i = 0; i < 8; i++) ones[i] = (bf16)1.0f;

  f32x16 o0 = fz16(), o1 = fz16(), lsum = fz16();

  char* lb = (char*)lKV;

  // LDS read offsets (R15-verified): row = l31 (+32 for half), parity bit in slot
  const int rb = l31 * 128;
  const int xb_ = 4 * ((l31 >> 3) & 1);
  const int cso0 = (((0 + l5) ^ (l & 7) ^ xb_) << 4);
  const int cso1 = (((2 + l5) ^ (l & 7) ^ xb_) << 4);
  const int cso2 = (((4 + l5) ^ (l & 7) ^ xb_) << 4);
  const int cso3 = (((6 + l5) ^ (l & 7) ^ xb_) << 4);

  // staging (R15-verified): 256 threads x 16B = 4KB/pass; K = 2 passes, V = 2
  const int row0 = tid >> 3;
  const int c8e = (((tid & 7) ^ (row0 & 7) ^ (4 * ((row0 >> 3) & 1))) << 3);
  int koff = row0 * HDIM + c8e + sp * 65536;        // split half: +1024 K-rows
  int voff = row0 * S_LEN + c8e + sp * 1024;        // split half: +1024 kv cols
  char* lkd = lb + w * 1024;                        // wave-uniform LDS dests
  char* lvd = lb + 8192 + w * 1024;

#define STAGE(B)                                                              \
  {                                                                           \
    gload16(Kh + koff,         lkd + (B));                                    \
    gload16(Kh + koff + 2048,  lkd + (B) + 4096);                             \
    gload16(Vh + voff,         lvd + (B));                                    \
    gload16(Vh + voff + 65536, lvd + (B) + 4096);                             \
    koff += 4096;                                                             \
    voff += 64;                                                               \
  }

  // One 32-key half: QK^T (4 chained MFMA), exp2, pack to two PV A-frags.
  // C-frag: lane reg r holds S[key = (r&3)+8*(r>>2)+4*l5][q = l31].
  // swap(low_pair, mid_pair): low.hi <-> mid.lo (v5b-verified operand order).
#define QKHALF(B, H, paA, paB)                                                \
  {                                                                           \
    const char* kB_ = lb + (B) + (H) * 4096;                                  \
    f32x16 s = fz16();                                                        \
    __builtin_amdgcn_s_setprio(1);                                            \
    bf16x8 kf0 = *(const bf16x8*)(kB_ + rb + cso0);                           \
    bf16x8 kf1 = *(const bf16x8*)(kB_ + rb + cso1);                           \
    bf16x8 kf2 = *(const bf16x8*)(kB_ + rb + cso2);                           \
    bf16x8 kf3 = *(const bf16x8*)(kB_ + rb + cso3);                           \
    s = mfma32(kf0, qf0, s);                                                  \
    s = mfma32(kf1, qf1, s);                                                  \
    s = mfma32(kf2, qf2, s);                                                  \
    s = mfma32(kf3, qf3, s);                                                  \
    __builtin_amdgcn_s_setprio(0);                                            \
    _Pragma("unroll") for (int r = 0; r < 16; r++)                            \
      s[r] = __builtin_amdgcn_exp2f(s[r]);                                    \
    {                                                                         \
      u32 a_ = cvt_pk_bf16(s[0], s[1]);                                       \
      u32 b_ = cvt_pk_bf16(s[2], s[3]);                                       \
      u32 c_ = cvt_pk_bf16(s[4], s[5]);                                       \
      u32 d_ = cvt_pk_bf16(s[6], s[7]);                                       \
      asm("v_permlane32_swap_b32 %0, %1" : "+v"(a_), "+v"(c_));               \
      asm("v_permlane32_swap_b32 %0, %1" : "+v"(b_), "+v"(d_));               \
      u32x4 t_ = {a_, b_, c_, d_};                                            \
      paA = __builtin_bit_cast(bf16x8, t_);                                   \
    }                                                                         \
    {                                                                         \
      u32 a_ = cvt_pk_bf16(s[8], s[9]);                                       \
      u32 b_ = cvt_pk_bf16(s[10], s[11]);                                     \
      u32 c_ = cvt_pk_bf16(s[12], s[13]);                                     \
      u32 d_ = cvt_pk_bf16(s[14], s[15]);                                     \
      asm("v_permlane32_swap_b32 %0, %1" : "+v"(a_), "+v"(c_));               \
      asm("v_permlane32_swap_b32 %0, %1" : "+v"(b_), "+v"(d_));               \
      u32x4 t_ = {a_, b_, c_, d_};                                            \
      paB = __builtin_bit_cast(bf16x8, t_);                                   \
    }                                                                         \
  }

#define COMPUTE(B)                                                            \
  {                                                                           \
    bf16x8 pa0, pa1, pa2, pa3;                                                \
    QKHALF(B, 0, pa0, pa1);                                                   \
    QKHALF(B, 1, pa2, pa3);                                                   \
    const char* vB_ = lb + (B) + 8192;                                        \
    __builtin_amdgcn_s_setprio(1);                                            \
    lsum = mfma32(pa0, ones, lsum);                                           \
    lsum = mfma32(pa1, ones, lsum);                                           \
    lsum = mfma32(pa2, ones, lsum);                                           \
    lsum = mfma32(pa3, ones, lsum);                                           \
    {                                                                         \
      bf16x8 vf0 = *(const bf16x8*)(vB_ + rb + cso0);                         \
      bf16x8 vf1 = *(const bf16x8*)(vB_ + rb + cso1);                         \
      bf16x8 vf2 = *(const bf16x8*)(vB_ + rb + cso2);                         \
      bf16x8 vf3 = *(const bf16x8*)(vB_ + rb + cso3);                         \
      o0 = mfma32(pa0, vf0, o0);                                              \
      o0 = mfma32(pa1, vf1, o0);                                              \
      o0 = mfma32(pa2, vf2, o0);                                              \
      o0 = mfma32(pa3, vf3, o0);                                              \
    }                                                                         \
    {                                                                         \
      bf16x8 vf0 = *(const bf16x8*)(vB_ + 4096 + rb + cso0);                  \
      bf16x8 vf1 = *(const bf16x8*)(vB_ + 4096 + rb + cso1);                  \
      bf16x8 vf2 = *(const bf16x8*)(vB_ + 4096 + rb + cso2);                  \
      bf16x8 vf3 = *(const bf16x8*)(vB_ + 4096 + rb + cso3);                  \
      o1 = mfma32(pa0, vf0, o1);                                              \
      o1 = mfma32(pa1, vf1, o1);                                              \
      o1 = mfma32(pa2, vf2, o1);                                              \
      o1 = mfma32(pa3, vf3, o1);                                              \
    }                                                                         \
    __builtin_amdgcn_s_setprio(0);                                            \
  }

  // prologue: stage tile 0 -> buf0
  STAGE(0);

  // main loop: 16 tiles of this split half, 2 x 16KB bufs, distance-1 prefetch.
  // iter t: [vmcnt(0): my tile-t loads landed] [barrier: everyone's landed AND
  // all waves done computing t-1 -> buf[(t+1)&1] free] [STAGE(t+1)] [COMPUTE(t)]
  for (int t = 0; t < 16; ++t) {
    asm volatile("s_waitcnt vmcnt(0)" ::: "memory");
    __builtin_amdgcn_s_barrier();
    __builtin_amdgcn_sched_barrier(0);
    if (t < 15) STAGE(((t + 1) & 1) << 14);
    COMPUTE((t & 1) << 14);
  }

#undef STAGE
#undef QKHALF
#undef COMPUTE

  // epilogue: write bf16 O-partials (OBUF layout [b*2048+s][h*64+d]) + fp32 lsum
  // C-frag: reg r -> q = (r&3) + 8*(r>>2) + 4*l5 ; col = l31 = d (within half)
  bf16* po = (sp == 0) ? po0 : po1;
  float* pl = plb + sp * 65536;
  const int bb = bh >> 4, h = bh & 15;
  const int srow0 = qt * 128 + w * 32;
#pragma unroll
  for (int r = 0; r < 16; r++) {
    int q = (r & 3) + 8 * (r >> 2) + 4 * l5;
    int s = srow0 + q;
    size_t base = ((size_t)(bb * 2048 + s)) * 1024 + h * 64 + l31;
    po[base]      = (bf16)o0[r];
    po[base + 32] = (bf16)o1[r];
    if (l31 == 0) pl[(bh << 11) + s] = lsum[r];   // lsum col-independent (B = ones)
  }
}

// ---------------- combine: obuf = (po0 + obuf) / (l_A + l_B), in place ----------------
__global__ void combine_kernel(const bf16* __restrict__ po0, const float* __restrict__ plb,
                               bf16* __restrict__ ob) {
  int idx = blockIdx.x * blockDim.x + threadIdx.x;  // 0 .. 524287 (8 elems each)
  size_t e = (size_t)idx * 8;
  int m = idx >> 7;              // b*2048+s  (0..4095)
  int h = (idx & 127) >> 3;      // 0..15
  int b = m >> 11, s = m & 2047;
  int lrow = ((b * 16 + h) << 11) + s;
  float inv = 1.0f / (plb[lrow] + plb[lrow + 65536]);
  bf16x8 a = *(const bf16x8*)(po0 + e);
  bf16x8 c = *(const bf16x8*)(ob + e);
  bf16x8 v;
#pragma unroll
  for (int i = 0; i < 8; i++)
    v[i] = (bf16)(((float)a[i] + (float)c[i]) * inv);
  *(bf16x8*)(ob + e) = v;
}

// ---------------- launch ----------------
extern "C" void kernel_launch(void* const* d_in, const int* in_sizes, int n_in,
                              void* d_out, int out_size, void* d_ws, size_t ws_size,
                              hipStream_t stream) {
  const float* x  = (const float*)d_in[0];
  const float* Wq = (const float*)d_in[1];
  const float* bq = (const float*)d_in[2];
  const float* Wk = (const float*)d_in[3];
  const float* bk = (const float*)d_in[4];
  const float* Wv = (const float*)d_in[5];
  const float* bv = (const float*)d_in[6];
  const float* Wo = (const float*)d_in[7];
  const float* bo = (const float*)d_in[8];
  float* out = (float*)d_out;

  char* ws = (char*)d_ws;
  bf16* xb    = (bf16*)(ws + (size_t)(0)  * (1 << 20));  // 8 MB  x bf16 [4096][1024]
  bf16* wqkvt = (bf16*)(ws + (size_t)(8)  * (1 << 20));  // 6 MB  [3072][1024]
  bf16* wot   = (bf16*)(ws + (size_t)(14) * (1 << 20));  // 2 MB  [1024][1024]
  bf16* qbuf  = (bf16*)(ws + (size_t)(16) * (1 << 20));  // 8 MB  [2][16][2048][64]
  bf16* kbuf  = (bf16*)(ws + (size_t)(24) * (1 << 20));  // 8 MB
  bf16* vtbuf = (bf16*)(ws + (size_t)(32) * (1 << 20));  // 8 MB  [2][16][64][2048]
  bf16* obuf  = (bf16*)(ws + (size_t)(40) * (1 << 20));  // 8 MB  [4096][1024]
  // partials overlay DEAD regions (stream-ordered): xb+wqkvt are consumed by
  // gemm0 before attn runs. Total ws usage stays at the proven 48 MB.
  bf16* po0   = (bf16*)(ws + (size_t)(0)  * (1 << 20));  // 8 MB  sp=0 partial (over xb)
  float* plb  = (float*)(ws + (size_t)(8) * (1 << 20));  // 512KB [2][65536] (over wqkvt)
  // sp=1 partial goes straight into obuf; combine normalizes in place.

  prep_x_kernel<<<dim3(2048), dim3(256), 0, stream>>>(x, xb);
  prep_w_kernel<<<dim3(16, 16, 4), dim3(256), 0, stream>>>(Wq, Wk, Wv, Wo, wqkvt, wot);
  gemm_bt<0><<<dim3(32, 24), dim3(256), 0, stream>>>(xb, wqkvt, bq, bk, bv,
                                                     nullptr, qbuf, kbuf, vtbuf);
  attn_kernel<<<dim3(1024), dim3(256), 0, stream>>>(qbuf, kbuf, vtbuf, po0, obuf, plb);
  combine_kernel<<<dim3(2048), dim3(256), 0, stream>>>(po0, plb, obuf);
  gemm_bt<1><<<dim3(32, 8), dim3(256), 0, stream>>>(obuf, wot, bo, nullptr, nullptr,
                                                    out, nullptr, nullptr, nullptr);
}